// Round 7
// baseline (1042.429 us; speedup 1.0000x reference)
//
#include <hip/hip_runtime.h>

#define NNODES 100000
#define NEDGES 1600000
#define FIN 256
#define HID 128
#define NG 128
#define SB 391            // ceil(NNODES/256)
#define NB 391            // buckets of 256 nodes (dst>>8)
#define NW 256            // histogram workgroups
#define EPW 6250          // NEDGES / NW

static constexpr float BN_EPS_C = 1e-5f;

typedef __attribute__((ext_vector_type(8))) short bf16x8;
typedef __attribute__((ext_vector_type(4))) float f32x4;

__device__ __forceinline__ float b2f(unsigned short u) {
    union { unsigned int i; float f; } c; c.i = ((unsigned int)u) << 16; return c.f;
}
__device__ __forceinline__ unsigned short f2b(float f) {
    union { float f; unsigned int i; } c; c.f = f;
    unsigned int u = c.i;
    u += 0x7fffu + ((u >> 16) & 1u);   // round-to-nearest-even
    return (unsigned short)(u >> 16);
}

__global__ __launch_bounds__(256) void k_zero_cnt(int* __restrict__ cnt) {
    int i = blockIdx.x * 256 + threadIdx.x;
    if (i < NNODES) cnt[i] = 0;
}

__global__ __launch_bounds__(256) void k_count(const int* __restrict__ dst, int* __restrict__ cnt) {
    int e = blockIdx.x * 256 + threadIdx.x;
    if (e < NEDGES) atomicAdd(&cnt[dst[e]], 1);
}

__global__ __launch_bounds__(256) void k_norm(const int* __restrict__ cnt,
                                              float* __restrict__ dis,
                                              float* __restrict__ selfn) {
    int i = blockIdx.x * 256 + threadIdx.x;
    if (i < NNODES) {
        float d = 1.0f + (float)cnt[i];
        dis[i] = rsqrtf(d);
        selfn[i] = 1.0f / d;
    }
}

__global__ __launch_bounds__(256) void k_scan1(const int* __restrict__ cnt, int* __restrict__ bsum) {
    __shared__ int s[256];
    int t = threadIdx.x;
    int i = blockIdx.x * 256 + t;
    s[t] = (i < NNODES) ? cnt[i] : 0;
    __syncthreads();
    for (int off = 128; off > 0; off >>= 1) {
        if (t < off) s[t] += s[t + off];
        __syncthreads();
    }
    if (t == 0) bsum[blockIdx.x] = s[0];
}

__global__ __launch_bounds__(512) void k_scan2(int* __restrict__ bsum) {
    __shared__ int s[512];
    int t = threadIdx.x;
    int v = (t < SB) ? bsum[t] : 0;
    s[t] = v;
    __syncthreads();
    for (int off = 1; off < 512; off <<= 1) {
        int a = (t >= off) ? s[t - off] : 0;
        __syncthreads();
        s[t] += a;
        __syncthreads();
    }
    if (t < SB) bsum[t] = s[t] - v;   // exclusive
}

__global__ __launch_bounds__(256) void k_scan3(const int* __restrict__ cnt,
                                               const int* __restrict__ bsum,
                                               int* __restrict__ rowptr) {
    __shared__ int s[256];
    int t = threadIdx.x;
    int i = blockIdx.x * 256 + t;
    int v = (i < NNODES) ? cnt[i] : 0;
    s[t] = v;
    __syncthreads();
    for (int off = 1; off < 256; off <<= 1) {
        int a = (t >= off) ? s[t - off] : 0;
        __syncthreads();
        s[t] += a;
        __syncthreads();
    }
    int ex = s[t] - v + bsum[blockIdx.x];
    if (i < NNODES) rowptr[i] = ex;
    if (i == 0) rowptr[NNODES] = NEDGES;
}

__global__ __launch_bounds__(256) void kbA(const int* __restrict__ dst, int* __restrict__ hist) {
    __shared__ int h[NB];
    int w = blockIdx.x, t = threadIdx.x;
    for (int i = t; i < NB; i += 256) h[i] = 0;
    __syncthreads();
    int base = w * EPW;
    for (int i = t; i < EPW; i += 256) atomicAdd(&h[dst[base + i] >> 8], 1);
    __syncthreads();
    for (int i = t; i < NB; i += 256) hist[i * NW + w] = h[i];
}

__global__ __launch_bounds__(256) void kbB(const int* __restrict__ rowptr,
                                           const int* __restrict__ hist,
                                           int* __restrict__ off) {
    __shared__ int s[NW];
    int b = blockIdx.x, t = threadIdx.x;
    int v = hist[b * NW + t];
    s[t] = v;
    __syncthreads();
    for (int o = 1; o < NW; o <<= 1) {
        int a = (t >= o) ? s[t - o] : 0;
        __syncthreads();
        s[t] += a;
        __syncthreads();
    }
    off[b * NW + t] = s[t] - v + rowptr[b * 256];
}

__global__ __launch_bounds__(256) void kbC(const int* __restrict__ src,
                                           const int* __restrict__ dst,
                                           const int* __restrict__ off,
                                           int* __restrict__ pairs) {
    __shared__ int cur[NB];
    int w = blockIdx.x, t = threadIdx.x;
    for (int i = t; i < NB; i += 256) cur[i] = off[i * NW + w];
    __syncthreads();
    int base = w * EPW;
    for (int i = t; i < EPW; i += 256) {
        int d = dst[base + i];
        int pos = atomicAdd(&cur[d >> 8], 1);
        pairs[pos] = (src[base + i] << 8) | (d & 255);
    }
}

__global__ __launch_bounds__(256) void kb2(const int* __restrict__ rowptr,
                                           const int* __restrict__ pairs,
                                           int* __restrict__ csr) {
    int b = blockIdx.x;
    int nbase = b * 256;
    int nmax = NNODES - nbase; if (nmax > 256) nmax = 256;
    __shared__ int cur[256];
    int t = threadIdx.x;
    if (t < nmax) cur[t] = rowptr[nbase + t];
    __syncthreads();
    int beg = rowptr[nbase];
    int end = rowptr[nbase + nmax];
    for (int i = beg + t; i < end; i += 256) {
        int p = pairs[i];
        int pos = atomicAdd(&cur[p & 255], 1);
        csr[pos] = p >> 8;
    }
}

// pack per-edge (src, u15 weight): edgp[e] = (src<<15) | round(dis[src]*dis[dst]*32767)
__global__ __launch_bounds__(256) void k_wedge(const int* __restrict__ rowptr,
                                               const int* __restrict__ csr,
                                               const float* __restrict__ dis,
                                               unsigned int* __restrict__ edgp) {
    int node = blockIdx.x * 4 + (threadIdx.x >> 6);
    if (node >= NNODES) return;
    int lane = threadIdx.x & 63;
    int beg = rowptr[node], end = rowptr[node + 1];
    float dd = dis[node];
    for (int i = beg + lane; i < end; i += 64) {
        int s = csr[i];
        float w = dis[s] * dd;
        unsigned int u = (unsigned int)(w * 32767.f + 0.5f);
        edgp[i] = ((unsigned int)s << 15) | u;
    }
}

// Convert W[K,128] fp32 -> hi/lo bf16 in MFMA frag-major layout
__global__ __launch_bounds__(256) void k_wconv(const float* __restrict__ W,
                                               unsigned short* __restrict__ whl,
                                               int K) {
    int idx = blockIdx.x * 256 + threadIdx.x;
    if (idx >= K * 128) return;
    int k = idx >> 7, c = idx & 127;
    float v = W[k * 128 + c];
    unsigned short hi = f2b(v);
    unsigned short lo = f2b(v - b2f(hi));
    int kstep = k >> 5, kk = k & 31, g = kk >> 3, j = kk & 7;
    int tile = c >> 4, lane = (c & 15) + 16 * g;
    size_t b0 = ((((size_t)kstep * 2 + 0) * 8 + tile) * 64 + lane) * 8 + j;
    size_t b1 = ((((size_t)kstep * 2 + 1) * 8 + tile) * 64 + lane) * 8 + j;
    whl[b0] = hi;
    whl[b1] = lo;
}

// MFMA split-bf16 GEMM: hw = A[N,K] @ W[K,128]; hwb (SLICED layout) = bf16(hw);
// ag = hw*selfn + bias. hwb_s[(slice*N + row)*16 + (col&15)], slice = col>>4.
template<int K, bool RELU_IN>
__global__ __launch_bounds__(256) void k_gemm_mfma(const float* __restrict__ A,
                                                   const unsigned short* __restrict__ whl,
                                                   const float* __restrict__ bias,
                                                   const float* __restrict__ selfn,
                                                   unsigned short* __restrict__ hwb,
                                                   float* __restrict__ ag) {
    __shared__ __align__(16) unsigned short Ah0[2048];
    __shared__ __align__(16) unsigned short Ah1[2048];
    __shared__ __align__(16) unsigned short Bs[8192];

    const int tid = threadIdx.x;
    const int w = tid >> 6;
    const int lane = tid & 63;
    const int m0 = blockIdx.x * 64;
    const int ar = tid >> 2;
    const int ak = (tid & 3) * 8;
    const int adst = (((ar >> 4) * 64) + (ar & 15) + 16 * (ak >> 3)) * 8;

    f32x4 acc[8] = {};

    for (int kt = 0; kt < K; kt += 32) {
        {
            float4 v0 = {0.f,0.f,0.f,0.f}, v1 = {0.f,0.f,0.f,0.f};
            int grow = m0 + ar;
            if (grow < NNODES) {
                const float* s = A + (size_t)grow * K + kt + ak;
                v0 = *(const float4*)(s);
                v1 = *(const float4*)(s + 4);
                if (RELU_IN) {
                    v0.x = fmaxf(v0.x, 0.f); v0.y = fmaxf(v0.y, 0.f);
                    v0.z = fmaxf(v0.z, 0.f); v0.w = fmaxf(v0.w, 0.f);
                    v1.x = fmaxf(v1.x, 0.f); v1.y = fmaxf(v1.y, 0.f);
                    v1.z = fmaxf(v1.z, 0.f); v1.w = fmaxf(v1.w, 0.f);
                }
            }
            float av[8];
            *(float4*)(av) = v0; *(float4*)(av + 4) = v1;
            bf16x8 hv, lv;
            #pragma unroll
            for (int j = 0; j < 8; ++j) {
                unsigned short h = f2b(av[j]);
                hv[j] = (short)h;
                lv[j] = (short)f2b(av[j] - b2f(h));
            }
            *(bf16x8*)&Ah0[adst] = hv;
            *(bf16x8*)&Ah1[adst] = lv;
        }
        {
            const float4* bsrc = (const float4*)(whl + (size_t)(kt >> 5) * 8192);
            float4* bdst = (float4*)Bs;
            #pragma unroll
            for (int i = 0; i < 4; ++i) bdst[tid * 4 + i] = bsrc[tid * 4 + i];
        }
        __syncthreads();
        bf16x8 a0 = *(const bf16x8*)&Ah0[(w * 64 + lane) * 8];
        bf16x8 a1 = *(const bf16x8*)&Ah1[(w * 64 + lane) * 8];
        #pragma unroll
        for (int t = 0; t < 8; ++t) {
            bf16x8 b0 = *(const bf16x8*)&Bs[(t * 64 + lane) * 8];
            bf16x8 b1 = *(const bf16x8*)&Bs[4096 + (t * 64 + lane) * 8];
            acc[t] = __builtin_amdgcn_mfma_f32_16x16x32_bf16(a0, b0, acc[t], 0, 0, 0);
            acc[t] = __builtin_amdgcn_mfma_f32_16x16x32_bf16(a0, b1, acc[t], 0, 0, 0);
            acc[t] = __builtin_amdgcn_mfma_f32_16x16x32_bf16(a1, b0, acc[t], 0, 0, 0);
        }
        __syncthreads();
    }

    const int colLo = lane & 15;
    const int gq = lane >> 4;
    float bbv[8];
    #pragma unroll
    for (int t = 0; t < 8; ++t) bbv[t] = bias[t * 16 + colLo];
    #pragma unroll
    for (int i = 0; i < 4; ++i) {
        int row = m0 + w * 16 + gq * 4 + i;
        if (row < NNODES) {
            float sn = selfn[row];
            #pragma unroll
            for (int t = 0; t < 8; ++t) {
                int col = t * 16 + colLo;
                float v = acc[t][i];
                hwb[((size_t)t * NNODES + row) * 16 + colLo] = f2b(v);
                ag[(size_t)row * HID + col] = fmaf(v, sn, bbv[t]);
            }
        }
    }
}

// feature-sliced gather: slice = blockIdx&7 (one slice per XCD under round-robin
// dispatch -> 3.2MB slice stays L2-resident). Wave = 1 node, 8 edges in flight
// (sub = lane>>3), lane handles 2 feats (fl = lane&7). Butterfly-reduce over sub.
__global__ __launch_bounds__(256) void k_gather(const int* __restrict__ rowptr,
                                                const unsigned int* __restrict__ edgp,
                                                const unsigned short* __restrict__ hwb,
                                                float* __restrict__ ag) {
    int slice = blockIdx.x & 7;
    int node = (blockIdx.x >> 3) * 4 + (threadIdx.x >> 6);
    int lane = threadIdx.x & 63;
    int sub = lane >> 3, fl = lane & 7;
    int beg = rowptr[node], end = rowptr[node + 1];
    const unsigned short* hs = hwb + (size_t)slice * NNODES * 16;
    float ax = 0.f, ay = 0.f;
    for (int e = beg; e < end; e += 8) {
        int ee = e + sub;
        int ec = ee < end ? ee : end - 1;
        unsigned int p = edgp[ec];
        int src = (int)(p >> 15);
        float w = (float)(p & 0x7fffu) * (1.0f / 32767.0f);
        if (ee >= end) w = 0.f;
        ushort2 r = *(const ushort2*)(hs + (size_t)src * 16 + fl * 2);
        ax += b2f(r.x) * w;
        ay += b2f(r.y) * w;
    }
    ax += __shfl_xor(ax, 8);  ay += __shfl_xor(ay, 8);
    ax += __shfl_xor(ax, 16); ay += __shfl_xor(ay, 16);
    ax += __shfl_xor(ax, 32); ay += __shfl_xor(ay, 32);
    if (sub == 0) {
        float2* agp = (float2*)&ag[(size_t)node * HID + slice * 16 + fl * 2];
        float2 s = *agp;
        s.x += ax; s.y += ay;
        *agp = s;
    }
}

__global__ __launch_bounds__(1024) void k_pool_bn(const float* __restrict__ h,
                                                  const int* __restrict__ batch,
                                                  const float* __restrict__ gamma,
                                                  const float* __restrict__ beta,
                                                  const float* __restrict__ mean,
                                                  const float* __restrict__ var,
                                                  float* __restrict__ xb) {
    int g = blockIdx.x;
    int tid = threadIdx.x;
    int f = tid & 127, r = tid >> 7;
    int a = 0, b = NNODES;
    while (a < b) { int m = (a + b) >> 1; if (batch[m] < g) a = m + 1; else b = m; }
    int s1 = a;
    b = NNODES;
    while (a < b) { int m = (a + b) >> 1; if (batch[m] < g + 1) a = m + 1; else b = m; }
    int e1 = a;
    float sum = 0.f;
    for (int i = s1 + r; i < e1; i += 8) sum += fmaxf(0.f, h[(size_t)i * HID + f]);
    __shared__ float red[8][128];
    red[r][f] = sum;
    __syncthreads();
    if (r == 0) {
        float s = red[0][f] + red[1][f] + red[2][f] + red[3][f]
                + red[4][f] + red[5][f] + red[6][f] + red[7][f];
        float cnt = (float)((e1 - s1) > 0 ? (e1 - s1) : 1);
        float pooled = s / cnt;
        float xbv = (pooled - mean[f]) * rsqrtf(var[f] + BN_EPS_C) * gamma[f] + beta[f];
        xb[g * HID + f] = xbv;
    }
}

__global__ __launch_bounds__(256) void k_head(const float* __restrict__ xb,
                                              const float* __restrict__ lw,
                                              const float* __restrict__ lb,
                                              float* __restrict__ out2) {
    int t = threadIdx.x;
    int g = t >> 1, c = t & 1;
    float s = lb[c];
    #pragma unroll
    for (int f = 0; f < HID; ++f) s = fmaf(xb[g * HID + f], lw[f * 2 + c], s);
    out2[t] = fmaxf(s, 0.f);
}

extern "C" void kernel_launch(void* const* d_in, const int* in_sizes, int n_in,
                              void* d_out, int out_size, void* d_ws, size_t ws_size,
                              hipStream_t stream) {
    const float* x     = (const float*)d_in[0];
    const int*   ei    = (const int*)d_in[1];
    const int*   batch = (const int*)d_in[3];
    const float* W1 = (const float*)d_in[4];
    const float* b1 = (const float*)d_in[5];
    const float* W2 = (const float*)d_in[6];
    const float* b2 = (const float*)d_in[7];
    const float* W3 = (const float*)d_in[8];
    const float* b3 = (const float*)d_in[9];
    const float* gamma = (const float*)d_in[10];
    const float* beta  = (const float*)d_in[11];
    const float* mean  = (const float*)d_in[12];
    const float* var   = (const float*)d_in[13];
    const float* lw = (const float*)d_in[14];
    const float* lb = (const float*)d_in[15];
    float* out = (float*)d_out;

    unsigned short* HWB = (unsigned short*)d_ws;                      // N*128 u16 (sliced layout)
    float* AG     = (float*)((char*)d_ws + (size_t)NNODES * HID * 2); // N*128 f
    float* DIS    = AG + (size_t)NNODES * HID;
    float* SELFN  = DIS + NNODES;
    int*   CNT    = (int*)(SELFN + NNODES);
    int*   ROWPTR = CNT + NNODES;
    int*   BSUM   = ROWPTR + NNODES + 64;
    int*   CSR    = BSUM + ((SB + 63) & ~63);
    unsigned int* EDGP = (unsigned int*)(CSR + NEDGES);               // E u32
    unsigned short* WHL1 = (unsigned short*)(((uintptr_t)(EDGP + NEDGES) + 15) & ~(uintptr_t)15);
    unsigned short* WHL2 = WHL1 + (size_t)FIN * 128 * 2;
    unsigned short* WHL3 = WHL2 + (size_t)HID * 128 * 2;
    // build-phase aliases (dead before first gemm writes HWB/AG)
    int*   PAIRS  = (int*)HWB;
    int*   HIST   = (int*)AG;
    int*   OFF    = HIST + NB * NW;

    const int* srcv = ei;
    const int* dstv = ei + NEDGES;

    const int gN = (NNODES + 255) / 256;
    const int gE = (NEDGES + 255) / 256;

    // ---- degree / norm / rowptr ----
    k_zero_cnt<<<gN, 256, 0, stream>>>(CNT);
    k_count<<<gE, 256, 0, stream>>>(dstv, CNT);
    k_norm<<<gN, 256, 0, stream>>>(CNT, DIS, SELFN);
    k_scan1<<<SB, 256, 0, stream>>>(CNT, BSUM);
    k_scan2<<<1, 512, 0, stream>>>(BSUM);
    k_scan3<<<SB, 256, 0, stream>>>(CNT, BSUM, ROWPTR);
    // ---- CSR build ----
    kbA<<<NW, 256, 0, stream>>>(dstv, HIST);
    kbB<<<NB, 256, 0, stream>>>(ROWPTR, HIST, OFF);
    kbC<<<NW, 256, 0, stream>>>(srcv, dstv, OFF, PAIRS);
    kb2<<<NB, 256, 0, stream>>>(ROWPTR, PAIRS, CSR);
    // ---- packed edge list (src + u15 weight) ----
    k_wedge<<<(NNODES + 3) / 4, 256, 0, stream>>>(ROWPTR, CSR, DIS, EDGP);
    // ---- W pre-conversion ----
    k_wconv<<<(FIN * 128 + 255) / 256, 256, 0, stream>>>(W1, WHL1, FIN);
    k_wconv<<<(HID * 128 + 255) / 256, 256, 0, stream>>>(W2, WHL2, HID);
    k_wconv<<<(HID * 128 + 255) / 256, 256, 0, stream>>>(W3, WHL3, HID);

    dim3 gg((NNODES + 63) / 64);
    const int ggat = ((NNODES + 3) / 4) * 8;   // node-groups x 8 slices

    // layer 1
    k_gemm_mfma<FIN, false><<<gg, 256, 0, stream>>>(x, WHL1, b1, SELFN, HWB, AG);
    k_gather<<<ggat, 256, 0, stream>>>(ROWPTR, EDGP, HWB, AG);
    // layer 2
    k_gemm_mfma<HID, true><<<gg, 256, 0, stream>>>(AG, WHL2, b2, SELFN, HWB, AG);
    k_gather<<<ggat, 256, 0, stream>>>(ROWPTR, EDGP, HWB, AG);
    // layer 3
    k_gemm_mfma<HID, true><<<gg, 256, 0, stream>>>(AG, WHL3, b3, SELFN, HWB, AG);
    k_gather<<<ggat, 256, 0, stream>>>(ROWPTR, EDGP, HWB, AG);

    k_pool_bn<<<NG, 1024, 0, stream>>>(AG, batch, gamma, beta, mean, var, out);
    k_head<<<1, 256, 0, stream>>>(out, lw, lb, out + (size_t)NG * HID);
}

// Round 8
// 512.025 us; speedup vs baseline: 2.0359x; 2.0359x over previous
//
#include <hip/hip_runtime.h>

#define NNODES 100000
#define NEDGES 1600000
#define FIN 256
#define HID 128
#define NG 128
#define SB 391            // ceil(NNODES/256)
#define NB 391            // buckets of 256 nodes (dst>>8)
#define NW 256            // histogram workgroups
#define EPW 6250          // NEDGES / NW

static constexpr float BN_EPS_C = 1e-5f;

typedef __attribute__((ext_vector_type(8))) short bf16x8;
typedef __attribute__((ext_vector_type(4))) float f32x4;

__device__ __forceinline__ float b2f(unsigned short u) {
    union { unsigned int i; float f; } c; c.i = ((unsigned int)u) << 16; return c.f;
}
__device__ __forceinline__ unsigned short f2b(float f) {
    union { float f; unsigned int i; } c; c.f = f;
    unsigned int u = c.i;
    u += 0x7fffu + ((u >> 16) & 1u);   // round-to-nearest-even
    return (unsigned short)(u >> 16);
}

__global__ __launch_bounds__(256) void k_zero_cnt(int* __restrict__ cnt) {
    int i = blockIdx.x * 256 + threadIdx.x;
    if (i < NNODES) cnt[i] = 0;
}

__global__ __launch_bounds__(256) void k_count(const int* __restrict__ dst, int* __restrict__ cnt) {
    int e = blockIdx.x * 256 + threadIdx.x;
    if (e < NEDGES) atomicAdd(&cnt[dst[e]], 1);
}

__global__ __launch_bounds__(256) void k_norm(const int* __restrict__ cnt,
                                              float* __restrict__ dis,
                                              float* __restrict__ selfn) {
    int i = blockIdx.x * 256 + threadIdx.x;
    if (i < NNODES) {
        float d = 1.0f + (float)cnt[i];
        dis[i] = rsqrtf(d);
        selfn[i] = 1.0f / d;
    }
}

__global__ __launch_bounds__(256) void k_scan1(const int* __restrict__ cnt, int* __restrict__ bsum) {
    __shared__ int s[256];
    int t = threadIdx.x;
    int i = blockIdx.x * 256 + t;
    s[t] = (i < NNODES) ? cnt[i] : 0;
    __syncthreads();
    for (int off = 128; off > 0; off >>= 1) {
        if (t < off) s[t] += s[t + off];
        __syncthreads();
    }
    if (t == 0) bsum[blockIdx.x] = s[0];
}

__global__ __launch_bounds__(512) void k_scan2(int* __restrict__ bsum) {
    __shared__ int s[512];
    int t = threadIdx.x;
    int v = (t < SB) ? bsum[t] : 0;
    s[t] = v;
    __syncthreads();
    for (int off = 1; off < 512; off <<= 1) {
        int a = (t >= off) ? s[t - off] : 0;
        __syncthreads();
        s[t] += a;
        __syncthreads();
    }
    if (t < SB) bsum[t] = s[t] - v;   // exclusive
}

__global__ __launch_bounds__(256) void k_scan3(const int* __restrict__ cnt,
                                               const int* __restrict__ bsum,
                                               int* __restrict__ rowptr) {
    __shared__ int s[256];
    int t = threadIdx.x;
    int i = blockIdx.x * 256 + t;
    int v = (i < NNODES) ? cnt[i] : 0;
    s[t] = v;
    __syncthreads();
    for (int off = 1; off < 256; off <<= 1) {
        int a = (t >= off) ? s[t - off] : 0;
        __syncthreads();
        s[t] += a;
        __syncthreads();
    }
    int ex = s[t] - v + bsum[blockIdx.x];
    if (i < NNODES) rowptr[i] = ex;
    if (i == 0) rowptr[NNODES] = NEDGES;
}

__global__ __launch_bounds__(256) void kbA(const int* __restrict__ dst, int* __restrict__ hist) {
    __shared__ int h[NB];
    int w = blockIdx.x, t = threadIdx.x;
    for (int i = t; i < NB; i += 256) h[i] = 0;
    __syncthreads();
    int base = w * EPW;
    for (int i = t; i < EPW; i += 256) atomicAdd(&h[dst[base + i] >> 8], 1);
    __syncthreads();
    for (int i = t; i < NB; i += 256) hist[i * NW + w] = h[i];
}

__global__ __launch_bounds__(256) void kbB(const int* __restrict__ rowptr,
                                           const int* __restrict__ hist,
                                           int* __restrict__ off) {
    __shared__ int s[NW];
    int b = blockIdx.x, t = threadIdx.x;
    int v = hist[b * NW + t];
    s[t] = v;
    __syncthreads();
    for (int o = 1; o < NW; o <<= 1) {
        int a = (t >= o) ? s[t - o] : 0;
        __syncthreads();
        s[t] += a;
        __syncthreads();
    }
    off[b * NW + t] = s[t] - v + rowptr[b * 256];
}

__global__ __launch_bounds__(256) void kbC(const int* __restrict__ src,
                                           const int* __restrict__ dst,
                                           const int* __restrict__ off,
                                           int* __restrict__ pairs) {
    __shared__ int cur[NB];
    int w = blockIdx.x, t = threadIdx.x;
    for (int i = t; i < NB; i += 256) cur[i] = off[i * NW + w];
    __syncthreads();
    int base = w * EPW;
    for (int i = t; i < EPW; i += 256) {
        int d = dst[base + i];
        int pos = atomicAdd(&cur[d >> 8], 1);
        pairs[pos] = (src[base + i] << 8) | (d & 255);
    }
}

__global__ __launch_bounds__(256) void kb2(const int* __restrict__ rowptr,
                                           const int* __restrict__ pairs,
                                           int* __restrict__ csr) {
    int b = blockIdx.x;
    int nbase = b * 256;
    int nmax = NNODES - nbase; if (nmax > 256) nmax = 256;
    __shared__ int cur[256];
    int t = threadIdx.x;
    if (t < nmax) cur[t] = rowptr[nbase + t];
    __syncthreads();
    int beg = rowptr[nbase];
    int end = rowptr[nbase + nmax];
    for (int i = beg + t; i < end; i += 256) {
        int p = pairs[i];
        int pos = atomicAdd(&cur[p & 255], 1);
        csr[pos] = p >> 8;
    }
}

// pack per-edge (src, u15 weight): edgp[e] = (src<<15) | round(dis[src]*dis[dst]*32767)
__global__ __launch_bounds__(256) void k_wedge(const int* __restrict__ rowptr,
                                               const int* __restrict__ csr,
                                               const float* __restrict__ dis,
                                               unsigned int* __restrict__ edgp) {
    int node = blockIdx.x * 4 + (threadIdx.x >> 6);
    if (node >= NNODES) return;
    int lane = threadIdx.x & 63;
    int beg = rowptr[node], end = rowptr[node + 1];
    float dd = dis[node];
    for (int i = beg + lane; i < end; i += 64) {
        int s = csr[i];
        float w = dis[s] * dd;
        unsigned int u = (unsigned int)(w * 32767.f + 0.5f);
        edgp[i] = ((unsigned int)s << 15) | u;
    }
}

// Convert W[K,128] fp32 -> hi/lo bf16 in MFMA frag-major layout
__global__ __launch_bounds__(256) void k_wconv(const float* __restrict__ W,
                                               unsigned short* __restrict__ whl,
                                               int K) {
    int idx = blockIdx.x * 256 + threadIdx.x;
    if (idx >= K * 128) return;
    int k = idx >> 7, c = idx & 127;
    float v = W[k * 128 + c];
    unsigned short hi = f2b(v);
    unsigned short lo = f2b(v - b2f(hi));
    int kstep = k >> 5, kk = k & 31, g = kk >> 3, j = kk & 7;
    int tile = c >> 4, lane = (c & 15) + 16 * g;
    size_t b0 = ((((size_t)kstep * 2 + 0) * 8 + tile) * 64 + lane) * 8 + j;
    size_t b1 = ((((size_t)kstep * 2 + 1) * 8 + tile) * 64 + lane) * 8 + j;
    whl[b0] = hi;
    whl[b1] = lo;
}

// MFMA split-bf16 GEMM: hw = A[N,K] @ W[K,128]; hwb = bf16(hw) row-major;
// ag = hw*selfn + bias.
template<int K, bool RELU_IN>
__global__ __launch_bounds__(256) void k_gemm_mfma(const float* __restrict__ A,
                                                   const unsigned short* __restrict__ whl,
                                                   const float* __restrict__ bias,
                                                   const float* __restrict__ selfn,
                                                   unsigned short* __restrict__ hwb,
                                                   float* __restrict__ ag) {
    __shared__ __align__(16) unsigned short Ah0[2048];
    __shared__ __align__(16) unsigned short Ah1[2048];
    __shared__ __align__(16) unsigned short Bs[8192];

    const int tid = threadIdx.x;
    const int w = tid >> 6;
    const int lane = tid & 63;
    const int m0 = blockIdx.x * 64;
    const int ar = tid >> 2;
    const int ak = (tid & 3) * 8;
    const int adst = (((ar >> 4) * 64) + (ar & 15) + 16 * (ak >> 3)) * 8;

    f32x4 acc[8] = {};

    for (int kt = 0; kt < K; kt += 32) {
        {
            float4 v0 = {0.f,0.f,0.f,0.f}, v1 = {0.f,0.f,0.f,0.f};
            int grow = m0 + ar;
            if (grow < NNODES) {
                const float* s = A + (size_t)grow * K + kt + ak;
                v0 = *(const float4*)(s);
                v1 = *(const float4*)(s + 4);
                if (RELU_IN) {
                    v0.x = fmaxf(v0.x, 0.f); v0.y = fmaxf(v0.y, 0.f);
                    v0.z = fmaxf(v0.z, 0.f); v0.w = fmaxf(v0.w, 0.f);
                    v1.x = fmaxf(v1.x, 0.f); v1.y = fmaxf(v1.y, 0.f);
                    v1.z = fmaxf(v1.z, 0.f); v1.w = fmaxf(v1.w, 0.f);
                }
            }
            float av[8];
            *(float4*)(av) = v0; *(float4*)(av + 4) = v1;
            bf16x8 hv, lv;
            #pragma unroll
            for (int j = 0; j < 8; ++j) {
                unsigned short h = f2b(av[j]);
                hv[j] = (short)h;
                lv[j] = (short)f2b(av[j] - b2f(h));
            }
            *(bf16x8*)&Ah0[adst] = hv;
            *(bf16x8*)&Ah1[adst] = lv;
        }
        {
            const float4* bsrc = (const float4*)(whl + (size_t)(kt >> 5) * 8192);
            float4* bdst = (float4*)Bs;
            #pragma unroll
            for (int i = 0; i < 4; ++i) bdst[tid * 4 + i] = bsrc[tid * 4 + i];
        }
        __syncthreads();
        bf16x8 a0 = *(const bf16x8*)&Ah0[(w * 64 + lane) * 8];
        bf16x8 a1 = *(const bf16x8*)&Ah1[(w * 64 + lane) * 8];
        #pragma unroll
        for (int t = 0; t < 8; ++t) {
            bf16x8 b0 = *(const bf16x8*)&Bs[(t * 64 + lane) * 8];
            bf16x8 b1 = *(const bf16x8*)&Bs[4096 + (t * 64 + lane) * 8];
            acc[t] = __builtin_amdgcn_mfma_f32_16x16x32_bf16(a0, b0, acc[t], 0, 0, 0);
            acc[t] = __builtin_amdgcn_mfma_f32_16x16x32_bf16(a0, b1, acc[t], 0, 0, 0);
            acc[t] = __builtin_amdgcn_mfma_f32_16x16x32_bf16(a1, b0, acc[t], 0, 0, 0);
        }
        __syncthreads();
    }

    const int colLo = lane & 15;
    const int gq = lane >> 4;
    float bbv[8];
    #pragma unroll
    for (int t = 0; t < 8; ++t) bbv[t] = bias[t * 16 + colLo];
    #pragma unroll
    for (int i = 0; i < 4; ++i) {
        int row = m0 + w * 16 + gq * 4 + i;
        if (row < NNODES) {
            float sn = selfn[row];
            #pragma unroll
            for (int t = 0; t < 8; ++t) {
                int col = t * 16 + colLo;
                float v = acc[t][i];
                hwb[(size_t)row * HID + col] = f2b(v);
                ag[(size_t)row * HID + col] = fmaf(v, sn, bbv[t]);
            }
        }
    }
}

// one wave per node; lane handles 2 features (bf16 rows, fp32 accumulate);
// packed edges (no dependent dis[] load), 8 edges in flight
__global__ __launch_bounds__(256) void k_gather(const int* __restrict__ rowptr,
                                                const unsigned int* __restrict__ edgp,
                                                const unsigned short* __restrict__ hwb,
                                                float* __restrict__ ag) {
    int node = blockIdx.x * 4 + (threadIdx.x >> 6);
    if (node >= NNODES) return;
    int lane = threadIdx.x & 63;
    int beg = rowptr[node], end = rowptr[node + 1];
    float2* agp = (float2*)&ag[(size_t)node * HID + lane * 2];
    float2 acc = *agp;
    int e = beg;
    for (; e + 7 < end; e += 8) {
        unsigned int p0 = edgp[e], p1 = edgp[e + 1], p2 = edgp[e + 2], p3 = edgp[e + 3];
        unsigned int p4 = edgp[e + 4], p5 = edgp[e + 5], p6 = edgp[e + 6], p7 = edgp[e + 7];
        ushort2 a0 = ((const ushort2*)(hwb + (size_t)(p0 >> 15) * HID))[lane];
        ushort2 a1 = ((const ushort2*)(hwb + (size_t)(p1 >> 15) * HID))[lane];
        ushort2 a2 = ((const ushort2*)(hwb + (size_t)(p2 >> 15) * HID))[lane];
        ushort2 a3 = ((const ushort2*)(hwb + (size_t)(p3 >> 15) * HID))[lane];
        ushort2 a4 = ((const ushort2*)(hwb + (size_t)(p4 >> 15) * HID))[lane];
        ushort2 a5 = ((const ushort2*)(hwb + (size_t)(p5 >> 15) * HID))[lane];
        ushort2 a6 = ((const ushort2*)(hwb + (size_t)(p6 >> 15) * HID))[lane];
        ushort2 a7 = ((const ushort2*)(hwb + (size_t)(p7 >> 15) * HID))[lane];
        const float q = 1.0f / 32767.0f;
        float w0 = (float)(p0 & 0x7fffu) * q, w1 = (float)(p1 & 0x7fffu) * q;
        float w2 = (float)(p2 & 0x7fffu) * q, w3 = (float)(p3 & 0x7fffu) * q;
        float w4 = (float)(p4 & 0x7fffu) * q, w5 = (float)(p5 & 0x7fffu) * q;
        float w6 = (float)(p6 & 0x7fffu) * q, w7 = (float)(p7 & 0x7fffu) * q;
        acc.x += b2f(a0.x) * w0 + b2f(a1.x) * w1 + b2f(a2.x) * w2 + b2f(a3.x) * w3
               + b2f(a4.x) * w4 + b2f(a5.x) * w5 + b2f(a6.x) * w6 + b2f(a7.x) * w7;
        acc.y += b2f(a0.y) * w0 + b2f(a1.y) * w1 + b2f(a2.y) * w2 + b2f(a3.y) * w3
               + b2f(a4.y) * w4 + b2f(a5.y) * w5 + b2f(a6.y) * w6 + b2f(a7.y) * w7;
    }
    for (; e < end; ++e) {
        unsigned int p = edgp[e];
        float w = (float)(p & 0x7fffu) * (1.0f / 32767.0f);
        ushort2 a0 = ((const ushort2*)(hwb + (size_t)(p >> 15) * HID))[lane];
        acc.x += b2f(a0.x) * w;
        acc.y += b2f(a0.y) * w;
    }
    *agp = acc;
}

__global__ __launch_bounds__(1024) void k_pool_bn(const float* __restrict__ h,
                                                  const int* __restrict__ batch,
                                                  const float* __restrict__ gamma,
                                                  const float* __restrict__ beta,
                                                  const float* __restrict__ mean,
                                                  const float* __restrict__ var,
                                                  float* __restrict__ xb) {
    int g = blockIdx.x;
    int tid = threadIdx.x;
    int f = tid & 127, r = tid >> 7;
    int a = 0, b = NNODES;
    while (a < b) { int m = (a + b) >> 1; if (batch[m] < g) a = m + 1; else b = m; }
    int s1 = a;
    b = NNODES;
    while (a < b) { int m = (a + b) >> 1; if (batch[m] < g + 1) a = m + 1; else b = m; }
    int e1 = a;
    float sum = 0.f;
    for (int i = s1 + r; i < e1; i += 8) sum += fmaxf(0.f, h[(size_t)i * HID + f]);
    __shared__ float red[8][128];
    red[r][f] = sum;
    __syncthreads();
    if (r == 0) {
        float s = red[0][f] + red[1][f] + red[2][f] + red[3][f]
                + red[4][f] + red[5][f] + red[6][f] + red[7][f];
        float cnt = (float)((e1 - s1) > 0 ? (e1 - s1) : 1);
        float pooled = s / cnt;
        float xbv = (pooled - mean[f]) * rsqrtf(var[f] + BN_EPS_C) * gamma[f] + beta[f];
        xb[g * HID + f] = xbv;
    }
}

__global__ __launch_bounds__(256) void k_head(const float* __restrict__ xb,
                                              const float* __restrict__ lw,
                                              const float* __restrict__ lb,
                                              float* __restrict__ out2) {
    int t = threadIdx.x;
    int g = t >> 1, c = t & 1;
    float s = lb[c];
    #pragma unroll
    for (int f = 0; f < HID; ++f) s = fmaf(xb[g * HID + f], lw[f * 2 + c], s);
    out2[t] = fmaxf(s, 0.f);
}

extern "C" void kernel_launch(void* const* d_in, const int* in_sizes, int n_in,
                              void* d_out, int out_size, void* d_ws, size_t ws_size,
                              hipStream_t stream) {
    const float* x     = (const float*)d_in[0];
    const int*   ei    = (const int*)d_in[1];
    const int*   batch = (const int*)d_in[3];
    const float* W1 = (const float*)d_in[4];
    const float* b1 = (const float*)d_in[5];
    const float* W2 = (const float*)d_in[6];
    const float* b2 = (const float*)d_in[7];
    const float* W3 = (const float*)d_in[8];
    const float* b3 = (const float*)d_in[9];
    const float* gamma = (const float*)d_in[10];
    const float* beta  = (const float*)d_in[11];
    const float* mean  = (const float*)d_in[12];
    const float* var   = (const float*)d_in[13];
    const float* lw = (const float*)d_in[14];
    const float* lb = (const float*)d_in[15];
    float* out = (float*)d_out;

    unsigned short* HWB = (unsigned short*)d_ws;                      // N*128 u16 row-major
    float* AG     = (float*)((char*)d_ws + (size_t)NNODES * HID * 2); // N*128 f
    float* DIS    = AG + (size_t)NNODES * HID;
    float* SELFN  = DIS + NNODES;
    int*   CNT    = (int*)(SELFN + NNODES);
    int*   ROWPTR = CNT + NNODES;
    int*   BSUM   = ROWPTR + NNODES + 64;
    int*   CSR    = BSUM + ((SB + 63) & ~63);
    unsigned int* EDGP = (unsigned int*)(CSR + NEDGES);               // E u32
    unsigned short* WHL1 = (unsigned short*)(((uintptr_t)(EDGP + NEDGES) + 15) & ~(uintptr_t)15);
    unsigned short* WHL2 = WHL1 + (size_t)FIN * 128 * 2;
    unsigned short* WHL3 = WHL2 + (size_t)HID * 128 * 2;
    // build-phase aliases (dead before first gemm writes HWB/AG)
    int*   PAIRS  = (int*)HWB;
    int*   HIST   = (int*)AG;
    int*   OFF    = HIST + NB * NW;

    const int* srcv = ei;
    const int* dstv = ei + NEDGES;

    const int gN = (NNODES + 255) / 256;
    const int gE = (NEDGES + 255) / 256;

    // ---- degree / norm / rowptr ----
    k_zero_cnt<<<gN, 256, 0, stream>>>(CNT);
    k_count<<<gE, 256, 0, stream>>>(dstv, CNT);
    k_norm<<<gN, 256, 0, stream>>>(CNT, DIS, SELFN);
    k_scan1<<<SB, 256, 0, stream>>>(CNT, BSUM);
    k_scan2<<<1, 512, 0, stream>>>(BSUM);
    k_scan3<<<SB, 256, 0, stream>>>(CNT, BSUM, ROWPTR);
    // ---- CSR build ----
    kbA<<<NW, 256, 0, stream>>>(dstv, HIST);
    kbB<<<NB, 256, 0, stream>>>(ROWPTR, HIST, OFF);
    kbC<<<NW, 256, 0, stream>>>(srcv, dstv, OFF, PAIRS);
    kb2<<<NB, 256, 0, stream>>>(ROWPTR, PAIRS, CSR);
    // ---- packed edge list (src + u15 weight) ----
    k_wedge<<<(NNODES + 3) / 4, 256, 0, stream>>>(ROWPTR, CSR, DIS, EDGP);
    // ---- W pre-conversion ----
    k_wconv<<<(FIN * 128 + 255) / 256, 256, 0, stream>>>(W1, WHL1, FIN);
    k_wconv<<<(HID * 128 + 255) / 256, 256, 0, stream>>>(W2, WHL2, HID);
    k_wconv<<<(HID * 128 + 255) / 256, 256, 0, stream>>>(W3, WHL3, HID);

    dim3 gg((NNODES + 63) / 64);
    const int ggat = (NNODES + 3) / 4;

    // layer 1
    k_gemm_mfma<FIN, false><<<gg, 256, 0, stream>>>(x, WHL1, b1, SELFN, HWB, AG);
    k_gather<<<ggat, 256, 0, stream>>>(ROWPTR, EDGP, HWB, AG);
    // layer 2
    k_gemm_mfma<HID, true><<<gg, 256, 0, stream>>>(AG, WHL2, b2, SELFN, HWB, AG);
    k_gather<<<ggat, 256, 0, stream>>>(ROWPTR, EDGP, HWB, AG);
    // layer 3
    k_gemm_mfma<HID, true><<<gg, 256, 0, stream>>>(AG, WHL3, b3, SELFN, HWB, AG);
    k_gather<<<ggat, 256, 0, stream>>>(ROWPTR, EDGP, HWB, AG);

    k_pool_bn<<<NG, 1024, 0, stream>>>(AG, batch, gamma, beta, mean, var, out);
    k_head<<<1, 256, 0, stream>>>(out, lw, lb, out + (size_t)NG * HID);
}

// Round 9
// 412.645 us; speedup vs baseline: 2.5262x; 1.2408x over previous
//
#include <hip/hip_runtime.h>

#define NNODES 100000
#define NEDGES 1600000
#define FIN 256
#define HID 128
#define NG 128
#define NB 391            // buckets of 256 nodes (dst>>8)
#define NW 256            // histogram workgroups
#define EPW 6250          // NEDGES / NW

static constexpr float BN_EPS_C = 1e-5f;

typedef __attribute__((ext_vector_type(8))) short bf16x8;
typedef __attribute__((ext_vector_type(4))) float f32x4;

__device__ __forceinline__ float b2f(unsigned short u) {
    union { unsigned int i; float f; } c; c.i = ((unsigned int)u) << 16; return c.f;
}
__device__ __forceinline__ unsigned short f2b(float f) {
    union { float f; unsigned int i; } c; c.f = f;
    unsigned int u = c.i;
    u += 0x7fffu + ((u >> 16) & 1u);   // round-to-nearest-even
    return (unsigned short)(u >> 16);
}

// pass A: per-WG LDS histogram over 391 buckets
__global__ __launch_bounds__(256) void kbA(const int* __restrict__ dst, int* __restrict__ hist) {
    __shared__ int h[NB];
    int w = blockIdx.x, t = threadIdx.x;
    for (int i = t; i < NB; i += 256) h[i] = 0;
    __syncthreads();
    int base = w * EPW;
    for (int i = t; i < EPW; i += 256) atomicAdd(&h[dst[base + i] >> 8], 1);
    __syncthreads();
    for (int i = t; i < NB; i += 256) hist[i * NW + w] = h[i];
}

// pass B: per-bucket exclusive scan across WGs (relative) + bucket totals
__global__ __launch_bounds__(256) void kbB2(const int* __restrict__ hist,
                                            int* __restrict__ off,
                                            int* __restrict__ btot) {
    __shared__ int s[NW];
    int b = blockIdx.x, t = threadIdx.x;
    int v = hist[b * NW + t];
    s[t] = v;
    __syncthreads();
    for (int o = 1; o < NW; o <<= 1) {
        int a = (t >= o) ? s[t - o] : 0;
        __syncthreads();
        s[t] += a;
        __syncthreads();
    }
    off[b * NW + t] = s[t] - v;
    if (t == NW - 1) btot[b] = s[t];
}

// bucket-base exclusive scan (one block)
__global__ __launch_bounds__(512) void kbT(const int* __restrict__ btot,
                                           int* __restrict__ bbase,
                                           int* __restrict__ rowptr) {
    __shared__ int s[512];
    int t = threadIdx.x;
    int v = (t < NB) ? btot[t] : 0;
    s[t] = v;
    __syncthreads();
    for (int o = 1; o < 512; o <<= 1) {
        int a = (t >= o) ? s[t - o] : 0;
        __syncthreads();
        s[t] += a;
        __syncthreads();
    }
    if (t < NB) bbase[t] = s[t] - v;
    if (t == NB - 1) { bbase[NB] = s[t]; rowptr[NNODES] = NEDGES; }
}

// pass C: scatter packed (src<<8 | dstLow) into bucket-contiguous regions
__global__ __launch_bounds__(256) void kbC2(const int* __restrict__ src,
                                            const int* __restrict__ dst,
                                            const int* __restrict__ off,
                                            const int* __restrict__ bbase,
                                            int* __restrict__ pairs) {
    __shared__ int cur[NB];
    int w = blockIdx.x, t = threadIdx.x;
    for (int i = t; i < NB; i += 256) cur[i] = off[i * NW + w] + bbase[i];
    __syncthreads();
    int base = w * EPW;
    for (int i = t; i < EPW; i += 256) {
        int d = dst[base + i];
        int pos = atomicAdd(&cur[d >> 8], 1);
        pairs[pos] = (src[base + i] << 8) | (d & 255);
    }
}

// per bucket: count per node (LDS), local scan -> rowptr/dis/selfn, then place CSR
__global__ __launch_bounds__(256) void kb2x(const int* __restrict__ bbase,
                                            const int* __restrict__ pairs,
                                            int* __restrict__ rowptr,
                                            float* __restrict__ dis,
                                            float* __restrict__ selfn,
                                            int* __restrict__ csr) {
    int b = blockIdx.x;
    int nbase = b * 256;
    int nmax = NNODES - nbase; if (nmax > 256) nmax = 256;
    __shared__ int cnt[256];
    __shared__ int cur[256];
    int t = threadIdx.x;
    cnt[t] = 0;
    __syncthreads();
    int beg = bbase[b], end = bbase[b + 1];
    for (int i = beg + t; i < end; i += 256) atomicAdd(&cnt[pairs[i] & 255], 1);
    __syncthreads();
    int v = cnt[t];
    cur[t] = v;
    __syncthreads();
    for (int o = 1; o < 256; o <<= 1) {
        int a = (t >= o) ? cur[t - o] : 0;
        __syncthreads();
        cur[t] += a;
        __syncthreads();
    }
    int ex = cur[t] - v + beg;
    if (t < nmax) {
        rowptr[nbase + t] = ex;
        float d = 1.0f + (float)v;
        dis[nbase + t] = rsqrtf(d);
        selfn[nbase + t] = 1.0f / d;
    }
    __syncthreads();
    cur[t] = ex;
    __syncthreads();
    for (int i = beg + t; i < end; i += 256) {
        int p = pairs[i];
        int pos = atomicAdd(&cur[p & 255], 1);
        csr[pos] = p >> 8;
    }
}

// pack per-edge (src, u15 weight): edgp[e] = (src<<15) | round(dis[src]*dis[dst]*32767)
__global__ __launch_bounds__(256) void k_wedge(const int* __restrict__ rowptr,
                                               const int* __restrict__ csr,
                                               const float* __restrict__ dis,
                                               unsigned int* __restrict__ edgp) {
    int node = blockIdx.x * 4 + (threadIdx.x >> 6);
    if (node >= NNODES) return;
    int lane = threadIdx.x & 63;
    int beg = rowptr[node], end = rowptr[node + 1];
    float dd = dis[node];
    for (int i = beg + lane; i < end; i += 64) {
        int s = csr[i];
        float w = dis[s] * dd;
        unsigned int u = (unsigned int)(w * 32767.f + 0.5f);
        edgp[i] = ((unsigned int)s << 15) | u;
    }
}

// Convert W[K,128] fp32 -> hi/lo bf16 in MFMA frag-major layout
__global__ __launch_bounds__(256) void k_wconv(const float* __restrict__ W,
                                               unsigned short* __restrict__ whl,
                                               int K) {
    int idx = blockIdx.x * 256 + threadIdx.x;
    if (idx >= K * 128) return;
    int k = idx >> 7, c = idx & 127;
    float v = W[k * 128 + c];
    unsigned short hi = f2b(v);
    unsigned short lo = f2b(v - b2f(hi));
    int kstep = k >> 5, kk = k & 31, g = kk >> 3, j = kk & 7;
    int tile = c >> 4, lane = (c & 15) + 16 * g;
    size_t b0 = ((((size_t)kstep * 2 + 0) * 8 + tile) * 64 + lane) * 8 + j;
    size_t b1 = ((((size_t)kstep * 2 + 1) * 8 + tile) * 64 + lane) * 8 + j;
    whl[b0] = hi;
    whl[b1] = lo;
}

// MFMA GEMM. MODE 0: A fp32, hi/lo split (3 MFMAs). MODE 1: A bf16 row-major (2 MFMAs).
// Epilogue: hwb = bf16(hw); ags = bf16(hw*selfn + bias)  (self-term, pre-neighbors)
template<int K, int MODE>
__global__ __launch_bounds__(256) void k_gemm_mfma(const void* __restrict__ Araw,
                                                   const unsigned short* __restrict__ whl,
                                                   const float* __restrict__ bias,
                                                   const float* __restrict__ selfn,
                                                   unsigned short* __restrict__ hwb,
                                                   unsigned short* __restrict__ ags) {
    __shared__ __align__(16) unsigned short Ah0[2048];
    __shared__ __align__(16) unsigned short Ah1[2048];
    __shared__ __align__(16) unsigned short Bs[8192];

    const int tid = threadIdx.x;
    const int w = tid >> 6;
    const int lane = tid & 63;
    const int m0 = blockIdx.x * 64;
    const int ar = tid >> 2;
    const int ak = (tid & 3) * 8;
    const int adst = (((ar >> 4) * 64) + (ar & 15) + 16 * (ak >> 3)) * 8;

    f32x4 acc[8] = {};

    for (int kt = 0; kt < K; kt += 32) {
        if (MODE == 0) {
            const float* A = (const float*)Araw;
            float4 v0 = {0.f,0.f,0.f,0.f}, v1 = {0.f,0.f,0.f,0.f};
            int grow = m0 + ar;
            if (grow < NNODES) {
                const float* s = A + (size_t)grow * K + kt + ak;
                v0 = *(const float4*)(s);
                v1 = *(const float4*)(s + 4);
            }
            float av[8];
            *(float4*)(av) = v0; *(float4*)(av + 4) = v1;
            bf16x8 hv, lv;
            #pragma unroll
            for (int j = 0; j < 8; ++j) {
                unsigned short h = f2b(av[j]);
                hv[j] = (short)h;
                lv[j] = (short)f2b(av[j] - b2f(h));
            }
            *(bf16x8*)&Ah0[adst] = hv;
            *(bf16x8*)&Ah1[adst] = lv;
        } else {
            const unsigned short* A = (const unsigned short*)Araw;
            bf16x8 hv = {};
            int grow = m0 + ar;
            if (grow < NNODES)
                hv = *(const bf16x8*)(A + (size_t)grow * K + kt + ak);
            *(bf16x8*)&Ah0[adst] = hv;
        }
        {
            const float4* bsrc = (const float4*)(whl + (size_t)(kt >> 5) * 8192);
            float4* bdst = (float4*)Bs;
            #pragma unroll
            for (int i = 0; i < 4; ++i) bdst[tid * 4 + i] = bsrc[tid * 4 + i];
        }
        __syncthreads();
        bf16x8 a0 = *(const bf16x8*)&Ah0[(w * 64 + lane) * 8];
        bf16x8 a1;
        if (MODE == 0) a1 = *(const bf16x8*)&Ah1[(w * 64 + lane) * 8];
        #pragma unroll
        for (int t = 0; t < 8; ++t) {
            bf16x8 b0 = *(const bf16x8*)&Bs[(t * 64 + lane) * 8];
            bf16x8 b1 = *(const bf16x8*)&Bs[4096 + (t * 64 + lane) * 8];
            acc[t] = __builtin_amdgcn_mfma_f32_16x16x32_bf16(a0, b0, acc[t], 0, 0, 0);
            acc[t] = __builtin_amdgcn_mfma_f32_16x16x32_bf16(a0, b1, acc[t], 0, 0, 0);
            if (MODE == 0)
                acc[t] = __builtin_amdgcn_mfma_f32_16x16x32_bf16(a1, b0, acc[t], 0, 0, 0);
        }
        __syncthreads();
    }

    const int colLo = lane & 15;
    const int gq = lane >> 4;
    float bbv[8];
    #pragma unroll
    for (int t = 0; t < 8; ++t) bbv[t] = bias[t * 16 + colLo];
    #pragma unroll
    for (int i = 0; i < 4; ++i) {
        int row = m0 + w * 16 + gq * 4 + i;
        if (row < NNODES) {
            float sn = selfn[row];
            #pragma unroll
            for (int t = 0; t < 8; ++t) {
                int col = t * 16 + colLo;
                float v = acc[t][i];
                hwb[(size_t)row * HID + col] = f2b(v);
                ags[(size_t)row * HID + col] = f2b(fmaf(v, sn, bbv[t]));
            }
        }
    }
}

// one wave per node; lane = 2 feats; 8 edges in flight.
// reads bf16 self-term ags, accumulates fp32, writes relu'd bf16 agb.
__global__ __launch_bounds__(256) void k_gather(const int* __restrict__ rowptr,
                                                const unsigned int* __restrict__ edgp,
                                                const unsigned short* __restrict__ hwb,
                                                const unsigned short* __restrict__ ags,
                                                unsigned short* __restrict__ agb) {
    int node = blockIdx.x * 4 + (threadIdx.x >> 6);
    if (node >= NNODES) return;
    int lane = threadIdx.x & 63;
    int beg = rowptr[node], end = rowptr[node + 1];
    ushort2 sv = ((const ushort2*)(ags + (size_t)node * HID))[lane];
    float2 acc; acc.x = b2f(sv.x); acc.y = b2f(sv.y);
    int e = beg;
    for (; e + 7 < end; e += 8) {
        unsigned int p0 = edgp[e], p1 = edgp[e + 1], p2 = edgp[e + 2], p3 = edgp[e + 3];
        unsigned int p4 = edgp[e + 4], p5 = edgp[e + 5], p6 = edgp[e + 6], p7 = edgp[e + 7];
        ushort2 a0 = ((const ushort2*)(hwb + (size_t)(p0 >> 15) * HID))[lane];
        ushort2 a1 = ((const ushort2*)(hwb + (size_t)(p1 >> 15) * HID))[lane];
        ushort2 a2 = ((const ushort2*)(hwb + (size_t)(p2 >> 15) * HID))[lane];
        ushort2 a3 = ((const ushort2*)(hwb + (size_t)(p3 >> 15) * HID))[lane];
        ushort2 a4 = ((const ushort2*)(hwb + (size_t)(p4 >> 15) * HID))[lane];
        ushort2 a5 = ((const ushort2*)(hwb + (size_t)(p5 >> 15) * HID))[lane];
        ushort2 a6 = ((const ushort2*)(hwb + (size_t)(p6 >> 15) * HID))[lane];
        ushort2 a7 = ((const ushort2*)(hwb + (size_t)(p7 >> 15) * HID))[lane];
        const float q = 1.0f / 32767.0f;
        float w0 = (float)(p0 & 0x7fffu) * q, w1 = (float)(p1 & 0x7fffu) * q;
        float w2 = (float)(p2 & 0x7fffu) * q, w3 = (float)(p3 & 0x7fffu) * q;
        float w4 = (float)(p4 & 0x7fffu) * q, w5 = (float)(p5 & 0x7fffu) * q;
        float w6 = (float)(p6 & 0x7fffu) * q, w7 = (float)(p7 & 0x7fffu) * q;
        acc.x += b2f(a0.x) * w0 + b2f(a1.x) * w1 + b2f(a2.x) * w2 + b2f(a3.x) * w3
               + b2f(a4.x) * w4 + b2f(a5.x) * w5 + b2f(a6.x) * w6 + b2f(a7.x) * w7;
        acc.y += b2f(a0.y) * w0 + b2f(a1.y) * w1 + b2f(a2.y) * w2 + b2f(a3.y) * w3
               + b2f(a4.y) * w4 + b2f(a5.y) * w5 + b2f(a6.y) * w6 + b2f(a7.y) * w7;
    }
    for (; e < end; ++e) {
        unsigned int p = edgp[e];
        float w = (float)(p & 0x7fffu) * (1.0f / 32767.0f);
        ushort2 a0 = ((const ushort2*)(hwb + (size_t)(p >> 15) * HID))[lane];
        acc.x += b2f(a0.x) * w;
        acc.y += b2f(a0.y) * w;
    }
    ushort2 o;
    o.x = f2b(fmaxf(acc.x, 0.f));
    o.y = f2b(fmaxf(acc.y, 0.f));
    ((ushort2*)(agb + (size_t)node * HID))[lane] = o;
}

// one graph per block, 1024 threads: 8 rows in flight per feature (agb is relu'd bf16)
__global__ __launch_bounds__(1024) void k_pool_bn(const unsigned short* __restrict__ h,
                                                  const int* __restrict__ batch,
                                                  const float* __restrict__ gamma,
                                                  const float* __restrict__ beta,
                                                  const float* __restrict__ mean,
                                                  const float* __restrict__ var,
                                                  float* __restrict__ xb) {
    int g = blockIdx.x;
    int tid = threadIdx.x;
    int f = tid & 127, r = tid >> 7;
    int a = 0, b = NNODES;
    while (a < b) { int m = (a + b) >> 1; if (batch[m] < g) a = m + 1; else b = m; }
    int s1 = a;
    b = NNODES;
    while (a < b) { int m = (a + b) >> 1; if (batch[m] < g + 1) a = m + 1; else b = m; }
    int e1 = a;
    float sum = 0.f;
    for (int i = s1 + r; i < e1; i += 8) sum += b2f(h[(size_t)i * HID + f]);
    __shared__ float red[8][128];
    red[r][f] = sum;
    __syncthreads();
    if (r == 0) {
        float s = red[0][f] + red[1][f] + red[2][f] + red[3][f]
                + red[4][f] + red[5][f] + red[6][f] + red[7][f];
        float cnt = (float)((e1 - s1) > 0 ? (e1 - s1) : 1);
        float pooled = s / cnt;
        float xbv = (pooled - mean[f]) * rsqrtf(var[f] + BN_EPS_C) * gamma[f] + beta[f];
        xb[g * HID + f] = xbv;
    }
}

__global__ __launch_bounds__(256) void k_head(const float* __restrict__ xb,
                                              const float* __restrict__ lw,
                                              const float* __restrict__ lb,
                                              float* __restrict__ out2) {
    int t = threadIdx.x;
    int g = t >> 1, c = t & 1;
    float s = lb[c];
    #pragma unroll
    for (int f = 0; f < HID; ++f) s = fmaf(xb[g * HID + f], lw[f * 2 + c], s);
    out2[t] = fmaxf(s, 0.f);
}

extern "C" void kernel_launch(void* const* d_in, const int* in_sizes, int n_in,
                              void* d_out, int out_size, void* d_ws, size_t ws_size,
                              hipStream_t stream) {
    const float* x     = (const float*)d_in[0];
    const int*   ei    = (const int*)d_in[1];
    const int*   batch = (const int*)d_in[3];
    const float* W1 = (const float*)d_in[4];
    const float* b1 = (const float*)d_in[5];
    const float* W2 = (const float*)d_in[6];
    const float* b2 = (const float*)d_in[7];
    const float* W3 = (const float*)d_in[8];
    const float* b3 = (const float*)d_in[9];
    const float* gamma = (const float*)d_in[10];
    const float* beta  = (const float*)d_in[11];
    const float* mean  = (const float*)d_in[12];
    const float* var   = (const float*)d_in[13];
    const float* lw = (const float*)d_in[14];
    const float* lb = (const float*)d_in[15];
    float* out = (float*)d_out;

    char* p = (char*)d_ws;
    unsigned short* HWB = (unsigned short*)p;          p += (size_t)NNODES * HID * 2;  // 25.6MB
    unsigned short* AGS = (unsigned short*)p;          p += (size_t)NNODES * HID * 2;  // 25.6MB
    unsigned short* AGB = (unsigned short*)p;          p += (size_t)NNODES * HID * 2;  // 25.6MB
    float* DIS    = (float*)p;                         p += (size_t)NNODES * 4;
    float* SELFN  = (float*)p;                         p += (size_t)NNODES * 4;
    int*   ROWPTR = (int*)p;                           p += (size_t)(NNODES + 64) * 4;
    int*   CSR    = (int*)p;                           p += (size_t)NEDGES * 4;
    unsigned int* EDGP = (unsigned int*)p;             p += (size_t)NEDGES * 4;
    int*   BTOT   = (int*)p;                           p += 512 * 4;
    int*   BBASE  = (int*)p;                           p += 512 * 4;
    unsigned short* WHL1 = (unsigned short*)p;         p += (size_t)FIN * 128 * 2 * 2;
    unsigned short* WHL2 = (unsigned short*)p;         p += (size_t)HID * 128 * 2 * 2;
    unsigned short* WHL3 = (unsigned short*)p;
    // build-phase aliases (consumed before gemm1/gather1 write HWB/AGS)
    int*   PAIRS  = (int*)HWB;                         // E i (6.4MB <= 25.6MB)
    int*   HIST   = (int*)AGS;                         // NB*NW i (400KB)
    int*   OFF    = HIST + NB * NW;                    // NB*NW i

    const int* srcv = ei;
    const int* dstv = ei + NEDGES;

    // ---- CSR build (histogram -> scans -> scatter -> count/place, no global atomics on nodes) ----
    kbA<<<NW, 256, 0, stream>>>(dstv, HIST);
    kbB2<<<NB, 256, 0, stream>>>(HIST, OFF, BTOT);
    kbT<<<1, 512, 0, stream>>>(BTOT, BBASE, ROWPTR);
    kbC2<<<NW, 256, 0, stream>>>(srcv, dstv, OFF, BBASE, PAIRS);
    kb2x<<<NB, 256, 0, stream>>>(BBASE, PAIRS, ROWPTR, DIS, SELFN, CSR);
    // ---- packed edge list (src + u15 weight) ----
    k_wedge<<<(NNODES + 3) / 4, 256, 0, stream>>>(ROWPTR, CSR, DIS, EDGP);
    // ---- W pre-conversion ----
    k_wconv<<<(FIN * 128 + 255) / 256, 256, 0, stream>>>(W1, WHL1, FIN);
    k_wconv<<<(HID * 128 + 255) / 256, 256, 0, stream>>>(W2, WHL2, HID);
    k_wconv<<<(HID * 128 + 255) / 256, 256, 0, stream>>>(W3, WHL3, HID);

    dim3 gg((NNODES + 63) / 64);
    const int ggat = (NNODES + 3) / 4;

    // layer 1 (A = fp32 x, hi/lo split)
    k_gemm_mfma<FIN, 0><<<gg, 256, 0, stream>>>(x, WHL1, b1, SELFN, HWB, AGS);
    k_gather<<<ggat, 256, 0, stream>>>(ROWPTR, EDGP, HWB, AGS, AGB);
    // layer 2 (A = relu'd bf16 AGB)
    k_gemm_mfma<HID, 1><<<gg, 256, 0, stream>>>(AGB, WHL2, b2, SELFN, HWB, AGS);
    k_gather<<<ggat, 256, 0, stream>>>(ROWPTR, EDGP, HWB, AGS, AGB);
    // layer 3
    k_gemm_mfma<HID, 1><<<gg, 256, 0, stream>>>(AGB, WHL3, b3, SELFN, HWB, AGS);
    k_gather<<<ggat, 256, 0, stream>>>(ROWPTR, EDGP, HWB, AGS, AGB);

    k_pool_bn<<<NG, 1024, 0, stream>>>(AGB, batch, gamma, beta, mean, var, out);
    k_head<<<1, 256, 0, stream>>>(out, lw, lb, out + (size_t)NG * HID);
}